// Round 2
// baseline (2261.642 us; speedup 1.0000x reference)
//
#include <hip/hip_runtime.h>

// AtomicScaleModule: CGCNN-style GNN forward, algebraically restructured.
//   a = atom_fea @ ae_w + ae_b
//   per layer l:
//     s = a @ msg_w1[l][0:64] + msg_b1[l]       } fused into producer of a
//     t = a @ msg_w1[l][64:128]                 }
//     H = sum_c relu(s[n] + t[idx[n,c]])          (k_gather, H overwrites S)
//     agg = H @ msg_w2[l] + 12*msg_b2[l]          (k_dense)
//     u1  = relu(a@upd_w1[l][0:64] + agg@upd_w1[l][64:128] + upd_b1[l])
//     a   = relu(a + u1 @ upd_w2[l] + upd_b2[l])
//   af = relu(a @ fx_w1 + fx_b1) @ fx_w2 + fx_b2 ; props = af @ prop_w^T + prop_b
// nbr_fea / ne_w / ne_b are dead in the reference.

constexpr int NA  = 300000;
constexpr int BLK = 128;

#define DEVFN __device__ __forceinline__

DEVFN float4 ld4(const float* p) { return *(const float4*)p; }
DEVFN void   st4(float* p, float4 v) { *(float4*)p = v; }
DEVFN void   fma4(float4& a, float s, float4 w) {
  a.x += s * w.x; a.y += s * w.y; a.z += s * w.z; a.w += s * w.w;
}
DEVFN float4 add4(float4 a, float4 b) {
  return make_float4(a.x + b.x, a.y + b.y, a.z + b.z, a.w + b.w);
}
DEVFN float4 relu4(float4 v) {
  return make_float4(fmaxf(v.x, 0.f), fmaxf(v.y, 0.f), fmaxf(v.z, 0.f), fmaxf(v.w, 0.f));
}

// acc[16] (64 outputs) += x (64 values, in regs) @ W[64][64], via a private
// LDS column xs[k][tid] so the dynamic k-loop never indexes a register array.
// No __syncthreads needed: each thread only touches its own column.
DEVFN void mv64(const float* __restrict__ W, float (*xs)[BLK], int t,
                const float4 (&x)[16], float4 (&acc)[16]) {
#pragma unroll
  for (int i = 0; i < 16; ++i) {
    xs[4 * i + 0][t] = x[i].x; xs[4 * i + 1][t] = x[i].y;
    xs[4 * i + 2][t] = x[i].z; xs[4 * i + 3][t] = x[i].w;
  }
#pragma unroll 1
  for (int k = 0; k < 64; k += 4) {
    float x0 = xs[k][t], x1 = xs[k + 1][t], x2 = xs[k + 2][t], x3 = xs[k + 3][t];
    const float* w = W + k * 64;
#pragma unroll
    for (int j = 0; j < 16; ++j) {
      fma4(acc[j], x0, ld4(w + j * 4));
      fma4(acc[j], x1, ld4(w + 64 + j * 4));
      fma4(acc[j], x2, ld4(w + 128 + j * 4));
      fma4(acc[j], x3, ld4(w + 192 + j * 4));
    }
  }
}

// embed + s,t for layer 0
__global__ __launch_bounds__(BLK) void k_embed_st(const float* __restrict__ X,
                                                  const float* __restrict__ W,
                                                  const float* __restrict__ b,
                                                  const float* __restrict__ W1,
                                                  const float* __restrict__ b1,
                                                  float* __restrict__ A0,
                                                  float* __restrict__ S,
                                                  float* __restrict__ T) {
  __shared__ float xs[64][BLK];
  int n = blockIdx.x * BLK + threadIdx.x;
  if (n >= NA) return;
  int t = threadIdx.x;
  float4 acc[16];
#pragma unroll
  for (int j = 0; j < 16; ++j) acc[j] = ld4(b + j * 4);
  const float* xr = X + (size_t)n * 92;
#pragma unroll 1
  for (int k = 0; k < 92; k += 4) {
    float4 x4 = ld4(xr + k);
    float xv[4] = {x4.x, x4.y, x4.z, x4.w};
    const float* w = W + k * 64;
#pragma unroll
    for (int kk = 0; kk < 4; ++kk) {
#pragma unroll
      for (int j = 0; j < 16; ++j) fma4(acc[j], xv[kk], ld4(w + kk * 64 + j * 4));
    }
  }
  float* ar = A0 + (size_t)n * 64;
#pragma unroll
  for (int j = 0; j < 16; ++j) st4(ar + j * 4, acc[j]);

  // s = a0 @ W1[0:64] + b1 ; t = a0 @ W1[64:128]
  float4 sv[16];
#pragma unroll
  for (int j = 0; j < 16; ++j) sv[j] = ld4(b1 + j * 4);
  mv64(W1, xs, t, acc, sv);
  float* sp = S + (size_t)n * 64;
#pragma unroll
  for (int j = 0; j < 16; ++j) st4(sp + j * 4, sv[j]);

  float4 tv[16];
#pragma unroll
  for (int j = 0; j < 16; ++j) tv[j] = make_float4(0, 0, 0, 0);
  mv64(W1 + 64 * 64, xs, t, acc, tv);
  float* tp = T + (size_t)n * 64;
#pragma unroll
  for (int j = 0; j < 16; ++j) st4(tp + j * 4, tv[j]);
}

// H[n] = sum_c relu(S[n] + T[idx[n,c]]); H overwrites S in place.
// thread = (atom n, float4-chunk c); each 16-lane group reads one
// contiguous 256B row per neighbor -> fully coalesced gather.
__global__ __launch_bounds__(256) void k_gather(float* __restrict__ S,
                                                const float* __restrict__ T,
                                                const int* __restrict__ IDX) {
  int tid = threadIdx.x;
  int n = blockIdx.x * 16 + (tid >> 4);
  int c = tid & 15;
  if (n >= NA) return;
  const int* ip = IDX + (size_t)n * 12;
  int4 i0 = *(const int4*)(ip);
  int4 i1 = *(const int4*)(ip + 4);
  int4 i2 = *(const int4*)(ip + 8);
  int idxs[12] = {i0.x, i0.y, i0.z, i0.w, i1.x, i1.y, i1.z, i1.w,
                  i2.x, i2.y, i2.z, i2.w};
  float* sp = S + (size_t)n * 64 + c * 4;
  float4 s4 = ld4(sp);
  float4 h = make_float4(0, 0, 0, 0);
#pragma unroll
  for (int j = 0; j < 12; ++j) {
    float4 t4 = ld4(T + (size_t)idxs[j] * 64 + c * 4);
    h = add4(h, relu4(add4(s4, t4)));
  }
  st4(sp, h);
}

// dense chain for layer l, plus fused s,t for layer l+1 (if has_next).
// H aliases S; this kernel reads its own H row then overwrites S row: safe.
__global__ __launch_bounds__(BLK) void k_dense(const float* __restrict__ A,
                                               const float* __restrict__ H,
                                               const float* __restrict__ W2,
                                               const float* __restrict__ b2,
                                               const float* __restrict__ U1,
                                               const float* __restrict__ ub1,
                                               const float* __restrict__ U2,
                                               const float* __restrict__ ub2,
                                               const float* __restrict__ Wn,
                                               const float* __restrict__ bn,
                                               float* __restrict__ Anew,
                                               float* __restrict__ S,
                                               float* __restrict__ T,
                                               int has_next) {
  __shared__ float xs[64][BLK];
  int n = blockIdx.x * BLK + threadIdx.x;
  if (n >= NA) return;
  int t = threadIdx.x;

  float4 ha[16];
#pragma unroll
  for (int j = 0; j < 16; ++j) ha[j] = ld4(H + (size_t)n * 64 + j * 4);

  // agg = H @ W2 + 12*b2
  float4 agg[16];
#pragma unroll
  for (int j = 0; j < 16; ++j) {
    float4 b = ld4(b2 + j * 4);
    agg[j] = make_float4(12.f * b.x, 12.f * b.y, 12.f * b.z, 12.f * b.w);
  }
  mv64(W2, xs, t, ha, agg);

  // u1 = relu(a @ U1[0:64] + agg @ U1[64:128] + ub1)
  float4 ar[16];
#pragma unroll
  for (int j = 0; j < 16; ++j) ar[j] = ld4(A + (size_t)n * 64 + j * 4);
  float4 u1[16];
#pragma unroll
  for (int j = 0; j < 16; ++j) u1[j] = ld4(ub1 + j * 4);
  mv64(U1, xs, t, ar, u1);
  mv64(U1 + 64 * 64, xs, t, agg, u1);
#pragma unroll
  for (int j = 0; j < 16; ++j) u1[j] = relu4(u1[j]);

  // a_new = relu(a + u1 @ U2 + ub2)
  float4 upd[16];
#pragma unroll
  for (int j = 0; j < 16; ++j) upd[j] = ld4(ub2 + j * 4);
  mv64(U2, xs, t, u1, upd);
  float4 an[16];
#pragma unroll
  for (int j = 0; j < 16; ++j) an[j] = relu4(add4(ar[j], upd[j]));
  float* ao = Anew + (size_t)n * 64;
#pragma unroll
  for (int j = 0; j < 16; ++j) st4(ao + j * 4, an[j]);

  if (has_next) {
    // s,t for next layer from a_new
    float4 sv[16];
#pragma unroll
    for (int j = 0; j < 16; ++j) sv[j] = ld4(bn + j * 4);
    mv64(Wn, xs, t, an, sv);
    float* sp = S + (size_t)n * 64;
#pragma unroll
    for (int j = 0; j < 16; ++j) st4(sp + j * 4, sv[j]);

    float4 tv[16];
#pragma unroll
    for (int j = 0; j < 16; ++j) tv[j] = make_float4(0, 0, 0, 0);
    mv64(Wn + 64 * 64, xs, t, an, tv);
    float* tp = T + (size_t)n * 64;
#pragma unroll
    for (int j = 0; j < 16; ++j) st4(tp + j * 4, tv[j]);
  }
}

__global__ __launch_bounds__(BLK) void k_fx(const float* __restrict__ Araw,
                                            const float* __restrict__ W1,  // [64][128]
                                            const float* __restrict__ b1,  // [128]
                                            const float* __restrict__ W2,  // [128][64]
                                            const float* __restrict__ b2,  // [64]
                                            const float* __restrict__ PW,  // [4][64]
                                            const float* __restrict__ PB,  // [4]
                                            float* __restrict__ AF,
                                            float* __restrict__ PR) {
  __shared__ float xs[64][BLK];
  int n = blockIdx.x * BLK + threadIdx.x;
  if (n >= NA) return;
  int t = threadIdx.x;

  float4 ar[16];
#pragma unroll
  for (int j = 0; j < 16; ++j) ar[j] = ld4(Araw + (size_t)n * 64 + j * 4);

  // h = relu(ar @ W1 + b1), 128 wide
  float4 h[32];
#pragma unroll
  for (int j = 0; j < 32; ++j) h[j] = ld4(b1 + j * 4);
#pragma unroll
  for (int i = 0; i < 16; ++i) {
    xs[4 * i + 0][t] = ar[i].x; xs[4 * i + 1][t] = ar[i].y;
    xs[4 * i + 2][t] = ar[i].z; xs[4 * i + 3][t] = ar[i].w;
  }
#pragma unroll 1
  for (int k = 0; k < 64; k += 2) {
    float x0 = xs[k][t], x1 = xs[k + 1][t];
    const float* w = W1 + k * 128;
#pragma unroll
    for (int j = 0; j < 32; ++j) {
      fma4(h[j], x0, ld4(w + j * 4));
      fma4(h[j], x1, ld4(w + 128 + j * 4));
    }
  }
#pragma unroll
  for (int j = 0; j < 32; ++j) h[j] = relu4(h[j]);

  // af = h @ W2 + b2  (K=128 in two halves through the LDS slot)
  float4 af[16];
#pragma unroll
  for (int j = 0; j < 16; ++j) af[j] = ld4(b2 + j * 4);
#pragma unroll
  for (int half = 0; half < 2; ++half) {
#pragma unroll
    for (int i = 0; i < 16; ++i) {
      float4 v = h[half * 16 + i];
      xs[4 * i + 0][t] = v.x; xs[4 * i + 1][t] = v.y;
      xs[4 * i + 2][t] = v.z; xs[4 * i + 3][t] = v.w;
    }
    const float* Wb = W2 + half * 64 * 64;
#pragma unroll 1
    for (int k = 0; k < 64; k += 4) {
      float x0 = xs[k][t], x1 = xs[k + 1][t], x2 = xs[k + 2][t], x3 = xs[k + 3][t];
      const float* w = Wb + k * 64;
#pragma unroll
      for (int j = 0; j < 16; ++j) {
        fma4(af[j], x0, ld4(w + j * 4));
        fma4(af[j], x1, ld4(w + 64 + j * 4));
        fma4(af[j], x2, ld4(w + 128 + j * 4));
        fma4(af[j], x3, ld4(w + 192 + j * 4));
      }
    }
  }

  // props = af @ PW^T + PB
  float pr[4];
#pragma unroll
  for (int p = 0; p < 4; ++p) {
    float s = PB[p];
#pragma unroll
    for (int i = 0; i < 16; ++i) {
      float4 w = ld4(PW + p * 64 + i * 4);
      s += af[i].x * w.x + af[i].y * w.y + af[i].z * w.z + af[i].w * w.w;
    }
    pr[p] = s;
  }

  float* afp = AF + (size_t)n * 64;
#pragma unroll
  for (int j = 0; j < 16; ++j) st4(afp + j * 4, af[j]);
  st4(PR + (size_t)n * 4, make_float4(pr[0], pr[1], pr[2], pr[3]));
}

extern "C" void kernel_launch(void* const* d_in, const int* in_sizes, int n_in,
                              void* d_out, int out_size, void* d_ws, size_t ws_size,
                              hipStream_t stream) {
  const float* atom_fea = (const float*)d_in[0];
  // d_in[1] nbr_fea, d_in[5] ne_w, d_in[6] ne_b: dead in the reference
  const int*   nbr_idx  = (const int*)d_in[2];
  const float* ae_w   = (const float*)d_in[3];
  const float* ae_b   = (const float*)d_in[4];
  const float* msg_w1 = (const float*)d_in[7];
  const float* msg_b1 = (const float*)d_in[8];
  const float* msg_w2 = (const float*)d_in[9];
  const float* msg_b2 = (const float*)d_in[10];
  const float* upd_w1 = (const float*)d_in[11];
  const float* upd_b1 = (const float*)d_in[12];
  const float* upd_w2 = (const float*)d_in[13];
  const float* upd_b2 = (const float*)d_in[14];
  const float* fx_w1  = (const float*)d_in[15];
  const float* fx_b1  = (const float*)d_in[16];
  const float* fx_w2  = (const float*)d_in[17];
  const float* fx_b2  = (const float*)d_in[18];
  const float* prop_w = (const float*)d_in[19];
  const float* prop_b = (const float*)d_in[20];

  float* props   = (float*)d_out;                 // [NA,4]
  float* af_reg  = props + (size_t)NA * 4;        // [NA,64]
  float* raw_reg = af_reg + (size_t)NA * 64;      // [NA,64]
  float* S = (float*)d_ws;                        // [NA,64] (also holds H)
  float* T = S + (size_t)NA * 64;                 // [NA,64]

  dim3 grid((NA + BLK - 1) / BLK), block(BLK);
  dim3 ggrid(NA / 16), gblock(256);               // 300000/16 = 18750 exact

  k_embed_st<<<grid, block, 0, stream>>>(atom_fea, ae_w, ae_b,
                                         msg_w1, msg_b1, af_reg, S, T);

  float* a_cur = af_reg;
  float* a_nxt = raw_reg;
  for (int l = 0; l < 3; ++l) {
    k_gather<<<ggrid, gblock, 0, stream>>>(S, T, nbr_idx);
    int has_next = (l < 2) ? 1 : 0;
    k_dense<<<grid, block, 0, stream>>>(
        a_cur, S,
        msg_w2 + (size_t)l * 64 * 64, msg_b2 + (size_t)l * 64,
        upd_w1 + (size_t)l * 128 * 64, upd_b1 + (size_t)l * 64,
        upd_w2 + (size_t)l * 64 * 64, upd_b2 + (size_t)l * 64,
        has_next ? msg_w1 + (size_t)(l + 1) * 128 * 64 : msg_w1,
        has_next ? msg_b1 + (size_t)(l + 1) * 64 : msg_b1,
        a_nxt, S, T, has_next);
    float* tmp = a_cur; a_cur = a_nxt; a_nxt = tmp;
  }
  // a_cur == raw_reg: final conv features ("raw" output)
  k_fx<<<grid, block, 0, stream>>>(a_cur, fx_w1, fx_b1, fx_w2, fx_b2,
                                   prop_w, prop_b, af_reg, props);
}

// Round 3
// 753.033 us; speedup vs baseline: 3.0034x; 3.0034x over previous
//
#include <hip/hip_runtime.h>

// AtomicScaleModule — CGCNN GNN forward, MFMA (split-bf16, ~f32 accuracy).
// Algebra (nbr_fea/ne_w/ne_b dead):
//   a = X@AE + ae_b
//   per layer: s = a@MW1[0:64]+b1 ; t = a@MW1[64:128]
//              H = sum_c relu(s + t[idx])            (k_gather; H over S)
//              agg = H@MW2 + 12*b2
//              u1 = relu(a@UW1[0:64] + agg@UW1[64:128] + ub1)
//              a' = relu(a + u1@UW2 + ub2)  (+ fused s,t of next layer)
//   af = relu(a@FX1+fb1)@FX2+fb2 ; props = af@PW^T+pb
// Precision: x@W ~= xh@Wh + xh@Wl + xl@Wh (3 MFMA), error ~2^-18 rel.

constexpr int NA = 300000;

typedef short  s16x8 __attribute__((ext_vector_type(8)));
typedef float  f32x4 __attribute__((ext_vector_type(4)));

#define DEVFN static __device__ __forceinline__

DEVFN unsigned short f2bf(float x) {
  unsigned u = __float_as_uint(x);
  u += 0x7fffu + ((u >> 16) & 1u);          // RTNE
  return (unsigned short)(u >> 16);
}
DEVFN float bf2f(unsigned short h) { return __uint_as_float(((unsigned)h) << 16); }

DEVFN void mk_frag(const float* v, s16x8& hi, s16x8& lo) {
#pragma unroll
  for (int i = 0; i < 8; ++i) {
    unsigned short h = f2bf(v[i]);
    hi[i] = (short)h;
    lo[i] = (short)f2bf(v[i] - bf2f(h));
  }
}

DEVFN f32x4 mf3(s16x8 ah, s16x8 al, s16x8 bh, s16x8 bl, f32x4 c) {
  c = __builtin_amdgcn_mfma_f32_16x16x32_bf16(al, bh, c, 0, 0, 0);
  c = __builtin_amdgcn_mfma_f32_16x16x32_bf16(ah, bl, c, 0, 0, 0);
  c = __builtin_amdgcn_mfma_f32_16x16x32_bf16(ah, bh, c, 0, 0, 0);
  return c;
}

// B-fragment load from pre-converted weight buffers.
DEVFN void ldB(const unsigned short* __restrict__ WH, const unsigned short* __restrict__ WL,
               int seg, int kt, int ct, int CT, int l, s16x8& bh, s16x8& bl) {
  size_t o = (size_t)seg + ((size_t)((kt * CT + ct) * 64 + l)) * 8;
  bh = *(const s16x8*)(WH + o);
  bl = *(const s16x8*)(WL + o);
}

// A-fragment from 8 contiguous f32 in global (16B-aligned).
DEVFN void ldA_g(const float* __restrict__ p8, s16x8& hi, s16x8& lo) {
  f32x4 a = *(const f32x4*)p8;
  f32x4 b = *(const f32x4*)(p8 + 4);
  float v[8] = {a[0], a[1], a[2], a[3], b[0], b[1], b[2], b[3]};
  mk_frag(v, hi, lo);
}

DEVFN void lds_fence() { asm volatile("s_waitcnt lgkmcnt(0)" ::: "memory"); }

// Wave-private transposed slab: sl[feature][atom(0..15)], pad 17.
// C-layout value (row=4g+r, col=16ct+m) -> sl[16ct+m][4g+r].
template <int NCT>
DEVFN void c_to_slab(float (*sl)[17], int m, int g, const f32x4 (&c)[NCT]) {
#pragma unroll
  for (int ct = 0; ct < NCT; ++ct)
#pragma unroll
    for (int r = 0; r < 4; ++r)
      sl[16 * ct + m][4 * g + r] = c[ct][r];
}

// A-frag for atom m, k = 32kt + 8g + i.
DEVFN void slab_frag(const float (*sl)[17], int m, int g, int kt, s16x8& hi, s16x8& lo) {
  float v[8];
#pragma unroll
  for (int i = 0; i < 8; ++i) v[i] = sl[32 * kt + 8 * g + i][m];
  mk_frag(v, hi, lo);
}

DEVFN void slab_store64(const float (*sl)[17], int m, int g, float* __restrict__ row, bool ok) {
  if (!ok) return;
#pragma unroll
  for (int p = 0; p < 4; ++p) {
    float4 q = make_float4(sl[16 * g + 4 * p + 0][m], sl[16 * g + 4 * p + 1][m],
                           sl[16 * g + 4 * p + 2][m], sl[16 * g + 4 * p + 3][m]);
    *(float4*)(row + 16 * g + 4 * p) = q;
  }
}

DEVFN void slab_storeT(const float (*sl)[17], int m, int g, unsigned short* __restrict__ row, bool ok) {
  if (!ok) return;
#pragma unroll
  for (int h = 0; h < 2; ++h) {
    uint4 q;
    unsigned* qp = (unsigned*)&q;
#pragma unroll
    for (int p = 0; p < 4; ++p) {
      float a = sl[16 * g + 8 * h + 2 * p + 0][m];
      float b = sl[16 * g + 8 * h + 2 * p + 1][m];
      qp[p] = (unsigned)f2bf(a) | ((unsigned)f2bf(b) << 16);
    }
    *(uint4*)(row + 16 * g + 8 * h) = q;
  }
}

// ---- weight pre-conversion to B-frag layout (hi/lo bf16) ------------------
// Segments (entry offsets): AE 0 (96x64); per layer base=6144+l*24576:
//   MW1 +0 (128x64), MW2 +8192 (64x64), UW1 +12288 (128x64), UW2 +20480 (64x64)
// FX1 79872 (64x128), FX2 88064 (128x64). Total 96256 entries.
__global__ __launch_bounds__(256) void k_prep(
    const float* __restrict__ ae, const float* __restrict__ mw1,
    const float* __restrict__ mw2, const float* __restrict__ uw1,
    const float* __restrict__ uw2, const float* __restrict__ fx1,
    const float* __restrict__ fx2,
    unsigned short* __restrict__ WH, unsigned short* __restrict__ WL) {
  int e = blockIdx.x * 256 + threadIdx.x;
  const float* src;
  int K, N, loc;
  if (e < 6144) { src = ae; K = 92; N = 64; loc = e; }
  else if (e < 79872) {
    int r = e - 6144;
    int lyr = r / 24576, q = r % 24576;
    size_t l64 = (size_t)lyr * 64;
    if (q < 8192)       { src = mw1 + l64 * 128; K = 128; N = 64; loc = q; }
    else if (q < 12288) { src = mw2 + l64 * 64;  K = 64;  N = 64; loc = q - 8192; }
    else if (q < 20480) { src = uw1 + l64 * 128; K = 128; N = 64; loc = q - 12288; }
    else                { src = uw2 + l64 * 64;  K = 64;  N = 64; loc = q - 20480; }
  }
  else if (e < 88064) { src = fx1; K = 64;  N = 128; loc = e - 79872; }
  else if (e < 96256) { src = fx2; K = 128; N = 64;  loc = e - 88064; }
  else return;
  int k = (N == 64) ? (loc >> 6) : (loc >> 7);
  int j = loc & (N - 1);
  float v = (k < K) ? src[(size_t)k * N + j] : 0.f;
  unsigned short h = f2bf(v);
  int CT = N >> 4;
  int lane = ((k >> 3) & 3) * 16 + (j & 15);
  int fidx = (e - loc) + (((k >> 5) * CT + (j >> 4)) * 64 + lane) * 8 + (k & 7);
  WH[fidx] = h;
  WL[fidx] = f2bf(v - bf2f(h));
}

// ---- embed + s,t of layer 0 ----------------------------------------------
__global__ __launch_bounds__(256) void k_embed_st(
    const float* __restrict__ X,
    const unsigned short* __restrict__ WH, const unsigned short* __restrict__ WL,
    const float* __restrict__ aeb, const float* __restrict__ b1,
    float* __restrict__ A0, float* __restrict__ S, unsigned short* __restrict__ T) {
  __shared__ float slab[4][64][17];
  int w = threadIdx.x >> 6, l = threadIdx.x & 63, m = l & 15, g = l >> 4;
  float (*sl)[17] = slab[w];
  int nbase = blockIdx.x * 128 + w * 32;
  int nat[2]; bool ok[2];
#pragma unroll
  for (int gr = 0; gr < 2; ++gr) {
    nat[gr] = nbase + gr * 16 + m;
    ok[gr] = nat[gr] < NA;
    if (!ok[gr]) nat[gr] = NA - 1;
  }

  // X fragments (K=92 padded to 96)
  s16x8 xh[2][3], xl[2][3];
#pragma unroll
  for (int gr = 0; gr < 2; ++gr) {
    const float* xr = X + (size_t)nat[gr] * 92;
#pragma unroll
    for (int kt = 0; kt < 3; ++kt) {
      float v[8];
      if (kt < 2) {
        f32x4 a = *(const f32x4*)(xr + kt * 32 + g * 8);
        f32x4 b = *(const f32x4*)(xr + kt * 32 + g * 8 + 4);
        v[0]=a[0]; v[1]=a[1]; v[2]=a[2]; v[3]=a[3]; v[4]=b[0]; v[5]=b[1]; v[6]=b[2]; v[7]=b[3];
      } else if (g < 3) {
        f32x4 a = *(const f32x4*)(xr + 64 + g * 8);
        f32x4 b = *(const f32x4*)(xr + 64 + g * 8 + 4);
        v[0]=a[0]; v[1]=a[1]; v[2]=a[2]; v[3]=a[3]; v[4]=b[0]; v[5]=b[1]; v[6]=b[2]; v[7]=b[3];
      } else {
        f32x4 a = *(const f32x4*)(xr + 88);   // 88..91 valid, 92..95 pad
        v[0]=a[0]; v[1]=a[1]; v[2]=a[2]; v[3]=a[3]; v[4]=0.f; v[5]=0.f; v[6]=0.f; v[7]=0.f;
      }
      mk_frag(v, xh[gr][kt], xl[gr][kt]);
    }
  }

  // a0 = X@AE + ae_b
  f32x4 ca[2][4];
#pragma unroll
  for (int gr = 0; gr < 2; ++gr)
#pragma unroll
    for (int ct = 0; ct < 4; ++ct)
#pragma unroll
      for (int r = 0; r < 4; ++r) ca[gr][ct][r] = 0.f;
#pragma unroll
  for (int ct = 0; ct < 4; ++ct)
#pragma unroll
    for (int kt = 0; kt < 3; ++kt) {
      s16x8 bh, bl; ldB(WH, WL, 0, kt, ct, 4, l, bh, bl);
      ca[0][ct] = mf3(xh[0][kt], xl[0][kt], bh, bl, ca[0][ct]);
      ca[1][ct] = mf3(xh[1][kt], xl[1][kt], bh, bl, ca[1][ct]);
    }
#pragma unroll
  for (int ct = 0; ct < 4; ++ct) {
    float bv = aeb[16 * ct + m];
#pragma unroll
    for (int r = 0; r < 4; ++r) { ca[0][ct][r] += bv; ca[1][ct][r] += bv; }
  }

  // relayout: store A0 + build a0 fragments
  s16x8 ah[2][2], al[2][2];
#pragma unroll
  for (int gr = 0; gr < 2; ++gr) {
    lds_fence();
    c_to_slab<4>(sl, m, g, ca[gr]);
    lds_fence();
    slab_store64(sl, m, g, A0 + (size_t)nat[gr] * 64, ok[gr]);
    slab_frag(sl, m, g, 0, ah[gr][0], al[gr][0]);
    slab_frag(sl, m, g, 1, ah[gr][1], al[gr][1]);
  }

  // s = a0@MW1[0:64] + b1
  f32x4 cs[2][4];
#pragma unroll
  for (int gr = 0; gr < 2; ++gr)
#pragma unroll
    for (int ct = 0; ct < 4; ++ct)
#pragma unroll
      for (int r = 0; r < 4; ++r) cs[gr][ct][r] = 0.f;
#pragma unroll
  for (int ct = 0; ct < 4; ++ct)
#pragma unroll
    for (int kt = 0; kt < 2; ++kt) {
      s16x8 bh, bl; ldB(WH, WL, 6144, kt, ct, 4, l, bh, bl);
      cs[0][ct] = mf3(ah[0][kt], al[0][kt], bh, bl, cs[0][ct]);
      cs[1][ct] = mf3(ah[1][kt], al[1][kt], bh, bl, cs[1][ct]);
    }
#pragma unroll
  for (int ct = 0; ct < 4; ++ct) {
    float bv = b1[16 * ct + m];
#pragma unroll
    for (int r = 0; r < 4; ++r) { cs[0][ct][r] += bv; cs[1][ct][r] += bv; }
  }
#pragma unroll
  for (int gr = 0; gr < 2; ++gr) {
    lds_fence();
    c_to_slab<4>(sl, m, g, cs[gr]);
    lds_fence();
    slab_store64(sl, m, g, S + (size_t)nat[gr] * 64, ok[gr]);
  }

  // t = a0@MW1[64:128]
  f32x4 cT[2][4];
#pragma unroll
  for (int gr = 0; gr < 2; ++gr)
#pragma unroll
    for (int ct = 0; ct < 4; ++ct)
#pragma unroll
      for (int r = 0; r < 4; ++r) cT[gr][ct][r] = 0.f;
#pragma unroll
  for (int ct = 0; ct < 4; ++ct)
#pragma unroll
    for (int kt = 0; kt < 2; ++kt) {
      s16x8 bh, bl; ldB(WH, WL, 6144, kt + 2, ct, 4, l, bh, bl);
      cT[0][ct] = mf3(ah[0][kt], al[0][kt], bh, bl, cT[0][ct]);
      cT[1][ct] = mf3(ah[1][kt], al[1][kt], bh, bl, cT[1][ct]);
    }
#pragma unroll
  for (int gr = 0; gr < 2; ++gr) {
    lds_fence();
    c_to_slab<4>(sl, m, g, cT[gr]);
    lds_fence();
    slab_storeT(sl, m, g, T + (size_t)nat[gr] * 64, ok[gr]);
  }
}

// ---- neighbor gather: H = sum_c relu(S + T[idx]) (in place over S) --------
__global__ __launch_bounds__(256) void k_gather(float* __restrict__ S,
                                                const unsigned short* __restrict__ T,
                                                const int* __restrict__ IDX) {
  int tid = blockIdx.x * 256 + threadIdx.x;
  int n = tid >> 4, c = tid & 15;
  if (n >= NA) return;
  const int* ip = IDX + (size_t)n * 12;
  int4 i0 = *(const int4*)ip;
  int4 i1 = *(const int4*)(ip + 4);
  int4 i2 = *(const int4*)(ip + 8);
  int idxs[12] = {i0.x, i0.y, i0.z, i0.w, i1.x, i1.y, i1.z, i1.w,
                  i2.x, i2.y, i2.z, i2.w};
  float* sp = S + (size_t)n * 64 + c * 4;
  float4 s4 = *(const float4*)sp;
  float4 h = make_float4(0, 0, 0, 0);
#pragma unroll
  for (int j = 0; j < 12; ++j) {
    uint2 tv = *(const uint2*)(T + (size_t)idxs[j] * 64 + c * 4);
    h.x += fmaxf(s4.x + bf2f((unsigned short)(tv.x & 0xffff)), 0.f);
    h.y += fmaxf(s4.y + bf2f((unsigned short)(tv.x >> 16)), 0.f);
    h.z += fmaxf(s4.z + bf2f((unsigned short)(tv.y & 0xffff)), 0.f);
    h.w += fmaxf(s4.w + bf2f((unsigned short)(tv.y >> 16)), 0.f);
  }
  *(float4*)sp = h;
}

// ---- dense chain of one conv layer (+ fused next-layer s,t) ---------------
__global__ __launch_bounds__(256) void k_dense(
    const float* __restrict__ A, const float* __restrict__ H,
    const unsigned short* __restrict__ WH, const unsigned short* __restrict__ WL,
    int segW2, int segU1, int segU2, int segWn,
    const float* __restrict__ b2, const float* __restrict__ ub1,
    const float* __restrict__ ub2, const float* __restrict__ bn,
    float* __restrict__ Anew, float* __restrict__ S, unsigned short* __restrict__ T,
    int has_next) {
  __shared__ float slab[4][64][17];
  int w = threadIdx.x >> 6, l = threadIdx.x & 63, m = l & 15, g = l >> 4;
  float (*sl)[17] = slab[w];
  int nbase = blockIdx.x * 128 + w * 32;
  int nat[2]; bool ok[2];
#pragma unroll
  for (int gr = 0; gr < 2; ++gr) {
    nat[gr] = nbase + gr * 16 + m;
    ok[gr] = nat[gr] < NA;
    if (!ok[gr]) nat[gr] = NA - 1;
  }

  // H fragments
  s16x8 hh[2][2], hl[2][2];
#pragma unroll
  for (int gr = 0; gr < 2; ++gr)
#pragma unroll
    for (int kt = 0; kt < 2; ++kt)
      ldA_g(H + (size_t)nat[gr] * 64 + kt * 32 + g * 8, hh[gr][kt], hl[gr][kt]);

  // agg = H@W2 + 12*b2
  f32x4 cg[2][4];
#pragma unroll
  for (int gr = 0; gr < 2; ++gr)
#pragma unroll
    for (int ct = 0; ct < 4; ++ct)
#pragma unroll
      for (int r = 0; r < 4; ++r) cg[gr][ct][r] = 0.f;
#pragma unroll
  for (int ct = 0; ct < 4; ++ct)
#pragma unroll
    for (int kt = 0; kt < 2; ++kt) {
      s16x8 bh, bl; ldB(WH, WL, segW2, kt, ct, 4, l, bh, bl);
      cg[0][ct] = mf3(hh[0][kt], hl[0][kt], bh, bl, cg[0][ct]);
      cg[1][ct] = mf3(hh[1][kt], hl[1][kt], bh, bl, cg[1][ct]);
    }
#pragma unroll
  for (int ct = 0; ct < 4; ++ct) {
    float bv = 12.f * b2[16 * ct + m];
#pragma unroll
    for (int r = 0; r < 4; ++r) { cg[0][ct][r] += bv; cg[1][ct][r] += bv; }
  }

  // agg fragments
  s16x8 qh[2][2], ql[2][2];
#pragma unroll
  for (int gr = 0; gr < 2; ++gr) {
    lds_fence();
    c_to_slab<4>(sl, m, g, cg[gr]);
    lds_fence();
    slab_frag(sl, m, g, 0, qh[gr][0], ql[gr][0]);
    slab_frag(sl, m, g, 1, qh[gr][1], ql[gr][1]);
  }

  // a fragments
  s16x8 arh[2][2], arl[2][2];
#pragma unroll
  for (int gr = 0; gr < 2; ++gr)
#pragma unroll
    for (int kt = 0; kt < 2; ++kt)
      ldA_g(A + (size_t)nat[gr] * 64 + kt * 32 + g * 8, arh[gr][kt], arl[gr][kt]);

  // u1 = relu(a@U1[0:64] + agg@U1[64:128] + ub1)
  f32x4 cu[2][4];
#pragma unroll
  for (int gr = 0; gr < 2; ++gr)
#pragma unroll
    for (int ct = 0; ct < 4; ++ct)
#pragma unroll
      for (int r = 0; r < 4; ++r) cu[gr][ct][r] = 0.f;
#pragma unroll
  for (int ct = 0; ct < 4; ++ct) {
#pragma unroll
    for (int kt = 0; kt < 2; ++kt) {
      s16x8 bh, bl; ldB(WH, WL, segU1, kt, ct, 4, l, bh, bl);
      cu[0][ct] = mf3(arh[0][kt], arl[0][kt], bh, bl, cu[0][ct]);
      cu[1][ct] = mf3(arh[1][kt], arl[1][kt], bh, bl, cu[1][ct]);
    }
#pragma unroll
    for (int kt = 0; kt < 2; ++kt) {
      s16x8 bh, bl; ldB(WH, WL, segU1, kt + 2, ct, 4, l, bh, bl);
      cu[0][ct] = mf3(qh[0][kt], ql[0][kt], bh, bl, cu[0][ct]);
      cu[1][ct] = mf3(qh[1][kt], ql[1][kt], bh, bl, cu[1][ct]);
    }
  }
#pragma unroll
  for (int ct = 0; ct < 4; ++ct) {
    float bv = ub1[16 * ct + m];
#pragma unroll
    for (int r = 0; r < 4; ++r) {
      cu[0][ct][r] = fmaxf(cu[0][ct][r] + bv, 0.f);
      cu[1][ct][r] = fmaxf(cu[1][ct][r] + bv, 0.f);
    }
  }

  // u1 fragments
  s16x8 uh[2][2], ul[2][2];
#pragma unroll
  for (int gr = 0; gr < 2; ++gr) {
    lds_fence();
    c_to_slab<4>(sl, m, g, cu[gr]);
    lds_fence();
    slab_frag(sl, m, g, 0, uh[gr][0], ul[gr][0]);
    slab_frag(sl, m, g, 1, uh[gr][1], ul[gr][1]);
  }

  // upd = u1@U2 + ub2 ; a' = relu(a + upd)
  f32x4 cd[2][4];
#pragma unroll
  for (int gr = 0; gr < 2; ++gr)
#pragma unroll
    for (int ct = 0; ct < 4; ++ct)
#pragma unroll
      for (int r = 0; r < 4; ++r) cd[gr][ct][r] = 0.f;
#pragma unroll
  for (int ct = 0; ct < 4; ++ct)
#pragma unroll
    for (int kt = 0; kt < 2; ++kt) {
      s16x8 bh, bl; ldB(WH, WL, segU2, kt, ct, 4, l, bh, bl);
      cd[0][ct] = mf3(uh[0][kt], ul[0][kt], bh, bl, cd[0][ct]);
      cd[1][ct] = mf3(uh[1][kt], ul[1][kt], bh, bl, cd[1][ct]);
    }
#pragma unroll
  for (int ct = 0; ct < 4; ++ct) {
    float bv = ub2[16 * ct + m];
#pragma unroll
    for (int gr = 0; gr < 2; ++gr)
#pragma unroll
      for (int r = 0; r < 4; ++r) {
        int nr = nbase + gr * 16 + 4 * g + r;
        if (nr > NA - 1) nr = NA - 1;
        float av = A[(size_t)nr * 64 + 16 * ct + m];
        cd[gr][ct][r] = fmaxf(av + cd[gr][ct][r] + bv, 0.f);
      }
  }

  // store a' (+ fragments for next-layer s,t)
  s16x8 anh[2][2], anl[2][2];
#pragma unroll
  for (int gr = 0; gr < 2; ++gr) {
    lds_fence();
    c_to_slab<4>(sl, m, g, cd[gr]);
    lds_fence();
    slab_store64(sl, m, g, Anew + (size_t)nat[gr] * 64, ok[gr]);
    if (has_next) {
      slab_frag(sl, m, g, 0, anh[gr][0], anl[gr][0]);
      slab_frag(sl, m, g, 1, anh[gr][1], anl[gr][1]);
    }
  }

  if (has_next) {
    // s_next
    f32x4 cs[2][4];
#pragma unroll
    for (int gr = 0; gr < 2; ++gr)
#pragma unroll
      for (int ct = 0; ct < 4; ++ct)
#pragma unroll
        for (int r = 0; r < 4; ++r) cs[gr][ct][r] = 0.f;
#pragma unroll
    for (int ct = 0; ct < 4; ++ct)
#pragma unroll
      for (int kt = 0; kt < 2; ++kt) {
        s16x8 bh, bl; ldB(WH, WL, segWn, kt, ct, 4, l, bh, bl);
        cs[0][ct] = mf3(anh[0][kt], anl[0][kt], bh, bl, cs[0][ct]);
        cs[1][ct] = mf3(anh[1][kt], anl[1][kt], bh, bl, cs[1][ct]);
      }
#pragma unroll
    for (int ct = 0; ct < 4; ++ct) {
      float bv = bn[16 * ct + m];
#pragma unroll
      for (int r = 0; r < 4; ++r) { cs[0][ct][r] += bv; cs[1][ct][r] += bv; }
    }
#pragma unroll
    for (int gr = 0; gr < 2; ++gr) {
      lds_fence();
      c_to_slab<4>(sl, m, g, cs[gr]);
      lds_fence();
      slab_store64(sl, m, g, S + (size_t)nat[gr] * 64, ok[gr]);
    }
    // t_next
    f32x4 cT[2][4];
#pragma unroll
    for (int gr = 0; gr < 2; ++gr)
#pragma unroll
      for (int ct = 0; ct < 4; ++ct)
#pragma unroll
        for (int r = 0; r < 4; ++r) cT[gr][ct][r] = 0.f;
#pragma unroll
    for (int ct = 0; ct < 4; ++ct)
#pragma unroll
      for (int kt = 0; kt < 2; ++kt) {
        s16x8 bh, bl; ldB(WH, WL, segWn, kt + 2, ct, 4, l, bh, bl);
        cT[0][ct] = mf3(anh[0][kt], anl[0][kt], bh, bl, cT[0][ct]);
        cT[1][ct] = mf3(anh[1][kt], anl[1][kt], bh, bl, cT[1][ct]);
      }
#pragma unroll
    for (int gr = 0; gr < 2; ++gr) {
      lds_fence();
      c_to_slab<4>(sl, m, g, cT[gr]);
      lds_fence();
      slab_storeT(sl, m, g, T + (size_t)nat[gr] * 64, ok[gr]);
    }
  }
}

// ---- feature extractor + props -------------------------------------------
__global__ __launch_bounds__(256) void k_fx(
    const float* __restrict__ Araw,
    const unsigned short* __restrict__ WH, const unsigned short* __restrict__ WL,
    const float* __restrict__ fb1, const float* __restrict__ fb2,
    const float* __restrict__ PW, const float* __restrict__ PB,
    float* __restrict__ AF, float* __restrict__ PR) {
  __shared__ float slab[4][128][17];
  int w = threadIdx.x >> 6, l = threadIdx.x & 63, m = l & 15, g = l >> 4;
  float (*sl)[17] = slab[w];
  int nbase = blockIdx.x * 128 + w * 32;
  int nat[2]; bool ok[2];
#pragma unroll
  for (int gr = 0; gr < 2; ++gr) {
    nat[gr] = nbase + gr * 16 + m;
    ok[gr] = nat[gr] < NA;
    if (!ok[gr]) nat[gr] = NA - 1;
  }

  s16x8 rh[2][2], rl[2][2];
#pragma unroll
  for (int gr = 0; gr < 2; ++gr)
#pragma unroll
    for (int kt = 0; kt < 2; ++kt)
      ldA_g(Araw + (size_t)nat[gr] * 64 + kt * 32 + g * 8, rh[gr][kt], rl[gr][kt]);

  // h = relu(raw@FX1 + fb1)  (128 wide)
  f32x4 ch[2][8];
#pragma unroll
  for (int gr = 0; gr < 2; ++gr)
#pragma unroll
    for (int ct = 0; ct < 8; ++ct)
#pragma unroll
      for (int r = 0; r < 4; ++r) ch[gr][ct][r] = 0.f;
#pragma unroll
  for (int ct = 0; ct < 8; ++ct)
#pragma unroll
    for (int kt = 0; kt < 2; ++kt) {
      s16x8 bh, bl; ldB(WH, WL, 79872, kt, ct, 8, l, bh, bl);
      ch[0][ct] = mf3(rh[0][kt], rl[0][kt], bh, bl, ch[0][ct]);
      ch[1][ct] = mf3(rh[1][kt], rl[1][kt], bh, bl, ch[1][ct]);
    }
#pragma unroll
  for (int ct = 0; ct < 8; ++ct) {
    float bv = fb1[16 * ct + m];
#pragma unroll
    for (int r = 0; r < 4; ++r) {
      ch[0][ct][r] = fmaxf(ch[0][ct][r] + bv, 0.f);
      ch[1][ct][r] = fmaxf(ch[1][ct][r] + bv, 0.f);
    }
  }

  // h fragments (K=128 -> 4 k-tiles)
  s16x8 hfh[2][4], hfl[2][4];
#pragma unroll
  for (int gr = 0; gr < 2; ++gr) {
    lds_fence();
    c_to_slab<8>(sl, m, g, ch[gr]);
    lds_fence();
#pragma unroll
    for (int kt = 0; kt < 4; ++kt) slab_frag(sl, m, g, kt, hfh[gr][kt], hfl[gr][kt]);
  }

  // af = h@FX2 + fb2
  f32x4 cf[2][4];
#pragma unroll
  for (int gr = 0; gr < 2; ++gr)
#pragma unroll
    for (int ct = 0; ct < 4; ++ct)
#pragma unroll
      for (int r = 0; r < 4; ++r) cf[gr][ct][r] = 0.f;
#pragma unroll
  for (int ct = 0; ct < 4; ++ct)
#pragma unroll
    for (int kt = 0; kt < 4; ++kt) {
      s16x8 bh, bl; ldB(WH, WL, 88064, kt, ct, 4, l, bh, bl);
      cf[0][ct] = mf3(hfh[0][kt], hfl[0][kt], bh, bl, cf[0][ct]);
      cf[1][ct] = mf3(hfh[1][kt], hfl[1][kt], bh, bl, cf[1][ct]);
    }
#pragma unroll
  for (int ct = 0; ct < 4; ++ct) {
    float bv = fb2[16 * ct + m];
#pragma unroll
    for (int r = 0; r < 4; ++r) { cf[0][ct][r] += bv; cf[1][ct][r] += bv; }
  }

  // store af + props
#pragma unroll
  for (int gr = 0; gr < 2; ++gr) {
    lds_fence();
    c_to_slab<4>(sl, m, g, cf[gr]);
    lds_fence();
    slab_store64(sl, m, g, AF + (size_t)nat[gr] * 64, ok[gr]);
    float acc = PB[g];
#pragma unroll 8
    for (int f = 0; f < 64; ++f) acc += sl[f][m] * PW[g * 64 + f];
    if (ok[gr]) PR[(size_t)nat[gr] * 4 + g] = acc;
  }
}

extern "C" void kernel_launch(void* const* d_in, const int* in_sizes, int n_in,
                              void* d_out, int out_size, void* d_ws, size_t ws_size,
                              hipStream_t stream) {
  const float* atom_fea = (const float*)d_in[0];
  const int*   nbr_idx  = (const int*)d_in[2];
  const float* ae_w   = (const float*)d_in[3];
  const float* ae_b   = (const float*)d_in[4];
  const float* msg_w1 = (const float*)d_in[7];
  const float* msg_b1 = (const float*)d_in[8];
  const float* msg_w2 = (const float*)d_in[9];
  const float* msg_b2 = (const float*)d_in[10];
  const float* upd_w1 = (const float*)d_in[11];
  const float* upd_b1 = (const float*)d_in[12];
  const float* upd_w2 = (const float*)d_in[13];
  const float* upd_b2 = (const float*)d_in[14];
  const float* fx_w1  = (const float*)d_in[15];
  const float* fx_b1  = (const float*)d_in[16];
  const float* fx_w2  = (const float*)d_in[17];
  const float* fx_b2  = (const float*)d_in[18];
  const float* prop_w = (const float*)d_in[19];
  const float* prop_b = (const float*)d_in[20];

  float* props   = (float*)d_out;
  float* af_reg  = props + (size_t)NA * 4;
  float* raw_reg = af_reg + (size_t)NA * 64;
  float* S = (float*)d_ws;
  unsigned short* T = (unsigned short*)(S + (size_t)NA * 64);
  unsigned short* WHp = T + (size_t)NA * 64;
  unsigned short* WLp = WHp + 96256;

  k_prep<<<376, 256, 0, stream>>>(ae_w, msg_w1, msg_w2, upd_w1, upd_w2,
                                  fx_w1, fx_w2, WHp, WLp);

  int ngrid = (NA + 127) / 128;   // 2344
  k_embed_st<<<ngrid, 256, 0, stream>>>(atom_fea, WHp, WLp, ae_b, msg_b1,
                                        af_reg, S, T);

  float* a_cur = af_reg;
  float* a_nxt = raw_reg;
  for (int lyr = 0; lyr < 3; ++lyr) {
    k_gather<<<(NA * 16) / 256, 256, 0, stream>>>(S, T, nbr_idx);
    int base = 6144 + lyr * 24576;
    int segWn = (lyr < 2) ? 6144 + (lyr + 1) * 24576 : 0;
    k_dense<<<ngrid, 256, 0, stream>>>(
        a_cur, S, WHp, WLp,
        base + 8192, base + 12288, base + 20480, segWn,
        msg_b2 + lyr * 64, upd_b1 + lyr * 64, upd_b2 + lyr * 64,
        (lyr < 2) ? msg_b1 + (lyr + 1) * 64 : msg_b1,
        a_nxt, S, T, (lyr < 2) ? 1 : 0);
    float* tmp = a_cur; a_cur = a_nxt; a_nxt = tmp;
  }
  // a_cur == raw_reg: final conv features
  k_fx<<<ngrid, 256, 0, stream>>>(a_cur, WHp, WLp, fx_b1, fx_b2,
                                  prop_w, prop_b, af_reg, props);
}

// Round 4
// 705.442 us; speedup vs baseline: 3.2060x; 1.0675x over previous
//
#include <hip/hip_runtime.h>
#include <hip/hip_bf16.h>

// AtomicScaleModule — CGCNN GNN forward, MFMA split-bf16 (~f32 accuracy),
// gather fused into the consumer dense kernel, fx fused into the last dense.
//   a = X@AE + ae_b
//   per layer: s = a@MW1[0:64]+b1 ; t = a@MW1[64:128]   (fused into producer)
//              H = sum_c relu(s + t[idx])               (gather @ head of dense)
//              agg = H@MW2 + 12*b2
//              u1 = relu(a@UW1[0:64] + agg@UW1[64:128] + ub1)
//              a' = relu(a + u1@UW2 + ub2)  (+ fused s,t of next layer)
//   af = relu(a@FX1+fb1)@FX2+fb2 ; props = af@PW^T+pb   (fused into last dense)
// S/T double-buffered across layers (dense reads layer-l S/T, writes l+1).
// nbr_fea / ne_w / ne_b are dead in the reference.

constexpr int NA = 300000;

typedef short  s16x8 __attribute__((ext_vector_type(8)));
typedef float  f32x4 __attribute__((ext_vector_type(4)));

#define DEVFN static __device__ __forceinline__

DEVFN unsigned short f2bf(float x) {
  unsigned u = __float_as_uint(x);
  u += 0x7fffu + ((u >> 16) & 1u);          // RTNE
  return (unsigned short)(u >> 16);
}
DEVFN float bf2f(unsigned short h) { return __uint_as_float(((unsigned)h) << 16); }

// split x -> hi + lo bf16 pair, via v_cvt_pk_bf16_f32-friendly pairs
DEVFN void mk_frag(const float* v, s16x8& hi, s16x8& lo) {
#pragma unroll
  for (int i = 0; i < 8; i += 2) {
    __hip_bfloat162 h2 = __float22bfloat162_rn(make_float2(v[i], v[i + 1]));
    float2 hf = __bfloat1622float2(h2);
    __hip_bfloat162 l2 = __float22bfloat162_rn(make_float2(v[i] - hf.x, v[i + 1] - hf.y));
    hi[i]     = (short)__bfloat16_as_ushort(h2.x);
    hi[i + 1] = (short)__bfloat16_as_ushort(h2.y);
    lo[i]     = (short)__bfloat16_as_ushort(l2.x);
    lo[i + 1] = (short)__bfloat16_as_ushort(l2.y);
  }
}

DEVFN f32x4 mf3(s16x8 ah, s16x8 al, s16x8 bh, s16x8 bl, f32x4 c) {
  c = __builtin_amdgcn_mfma_f32_16x16x32_bf16(al, bh, c, 0, 0, 0);
  c = __builtin_amdgcn_mfma_f32_16x16x32_bf16(ah, bl, c, 0, 0, 0);
  c = __builtin_amdgcn_mfma_f32_16x16x32_bf16(ah, bh, c, 0, 0, 0);
  return c;
}

DEVFN void ldB(const unsigned short* __restrict__ WH, const unsigned short* __restrict__ WL,
               int seg, int kt, int ct, int CT, int l, s16x8& bh, s16x8& bl) {
  size_t o = (size_t)seg + ((size_t)((kt * CT + ct) * 64 + l)) * 8;
  bh = *(const s16x8*)(WH + o);
  bl = *(const s16x8*)(WL + o);
}

DEVFN void ldA_g(const float* __restrict__ p8, s16x8& hi, s16x8& lo) {
  f32x4 a = *(const f32x4*)p8;
  f32x4 b = *(const f32x4*)(p8 + 4);
  float v[8] = {a[0], a[1], a[2], a[3], b[0], b[1], b[2], b[3]};
  mk_frag(v, hi, lo);
}

DEVFN void lds_fence() { asm volatile("s_waitcnt lgkmcnt(0)" ::: "memory"); }

// Wave-private transposed slab: sl[feature][atom(0..15)], pad 17.
template <int NCT>
DEVFN void c_to_slab(float (*sl)[17], int m, int g, const f32x4 (&c)[NCT]) {
#pragma unroll
  for (int ct = 0; ct < NCT; ++ct)
#pragma unroll
    for (int r = 0; r < 4; ++r)
      sl[16 * ct + m][4 * g + r] = c[ct][r];
}

DEVFN void slab_frag(const float (*sl)[17], int m, int g, int kt, s16x8& hi, s16x8& lo) {
  float v[8];
#pragma unroll
  for (int i = 0; i < 8; ++i) v[i] = sl[32 * kt + 8 * g + i][m];
  mk_frag(v, hi, lo);
}

DEVFN void slab_store64(const float (*sl)[17], int m, int g, float* __restrict__ row, bool ok) {
  if (!ok) return;
#pragma unroll
  for (int p = 0; p < 4; ++p) {
    float4 q = make_float4(sl[16 * g + 4 * p + 0][m], sl[16 * g + 4 * p + 1][m],
                           sl[16 * g + 4 * p + 2][m], sl[16 * g + 4 * p + 3][m]);
    *(float4*)(row + 16 * g + 4 * p) = q;
  }
}

DEVFN void slab_storeT(const float (*sl)[17], int m, int g, unsigned short* __restrict__ row, bool ok) {
  if (!ok) return;
#pragma unroll
  for (int h = 0; h < 2; ++h) {
    uint4 q;
    unsigned* qp = (unsigned*)&q;
#pragma unroll
    for (int p = 0; p < 4; ++p) {
      float a = sl[16 * g + 8 * h + 2 * p + 0][m];
      float b = sl[16 * g + 8 * h + 2 * p + 1][m];
      qp[p] = (unsigned)f2bf(a) | ((unsigned)f2bf(b) << 16);
    }
    *(uint4*)(row + 16 * g + 8 * h) = q;
  }
}

// ---- weight pre-conversion to B-frag layout (hi/lo bf16) ------------------
// Segments (entry offsets): AE 0 (96x64); per layer base=6144+l*24576:
//   MW1 +0 (128x64), MW2 +8192 (64x64), UW1 +12288 (128x64), UW2 +20480 (64x64)
// FX1 79872 (64x128), FX2 88064 (128x64). Total 96256 entries.
__global__ __launch_bounds__(256) void k_prep(
    const float* __restrict__ ae, const float* __restrict__ mw1,
    const float* __restrict__ mw2, const float* __restrict__ uw1,
    const float* __restrict__ uw2, const float* __restrict__ fx1,
    const float* __restrict__ fx2,
    unsigned short* __restrict__ WH, unsigned short* __restrict__ WL) {
  int e = blockIdx.x * 256 + threadIdx.x;
  const float* src;
  int K, N, loc;
  if (e < 6144) { src = ae; K = 92; N = 64; loc = e; }
  else if (e < 79872) {
    int r = e - 6144;
    int lyr = r / 24576, q = r % 24576;
    size_t l64 = (size_t)lyr * 64;
    if (q < 8192)       { src = mw1 + l64 * 128; K = 128; N = 64; loc = q; }
    else if (q < 12288) { src = mw2 + l64 * 64;  K = 64;  N = 64; loc = q - 8192; }
    else if (q < 20480) { src = uw1 + l64 * 128; K = 128; N = 64; loc = q - 12288; }
    else                { src = uw2 + l64 * 64;  K = 64;  N = 64; loc = q - 20480; }
  }
  else if (e < 88064) { src = fx1; K = 64;  N = 128; loc = e - 79872; }
  else if (e < 96256) { src = fx2; K = 128; N = 64;  loc = e - 88064; }
  else return;
  int k = (N == 64) ? (loc >> 6) : (loc >> 7);
  int j = loc & (N - 1);
  float v = (k < K) ? src[(size_t)k * N + j] : 0.f;
  unsigned short h = f2bf(v);
  int CT = N >> 4;
  int lane = ((k >> 3) & 3) * 16 + (j & 15);
  int fidx = (e - loc) + (((k >> 5) * CT + (j >> 4)) * 64 + lane) * 8 + (k & 7);
  WH[fidx] = h;
  WL[fidx] = f2bf(v - bf2f(h));
}

// ---- embed + s,t of layer 0 ----------------------------------------------
__global__ __launch_bounds__(256) void k_embed_st(
    const float* __restrict__ X,
    const unsigned short* __restrict__ WH, const unsigned short* __restrict__ WL,
    const float* __restrict__ aeb, const float* __restrict__ b1,
    float* __restrict__ A0, float* __restrict__ S, unsigned short* __restrict__ T) {
  __shared__ float slab[4][64][17];
  int w = threadIdx.x >> 6, l = threadIdx.x & 63, m = l & 15, g = l >> 4;
  float (*sl)[17] = slab[w];
  int nbase = blockIdx.x * 128 + w * 32;
  int nat[2]; bool ok[2];
#pragma unroll
  for (int gr = 0; gr < 2; ++gr) {
    nat[gr] = nbase + gr * 16 + m;
    ok[gr] = nat[gr] < NA;
    if (!ok[gr]) nat[gr] = NA - 1;
  }

  s16x8 xh[2][3], xl[2][3];
#pragma unroll
  for (int gr = 0; gr < 2; ++gr) {
    const float* xr = X + (size_t)nat[gr] * 92;
#pragma unroll
    for (int kt = 0; kt < 3; ++kt) {
      float v[8];
      if (kt < 2) {
        f32x4 a = *(const f32x4*)(xr + kt * 32 + g * 8);
        f32x4 b = *(const f32x4*)(xr + kt * 32 + g * 8 + 4);
        v[0]=a[0]; v[1]=a[1]; v[2]=a[2]; v[3]=a[3]; v[4]=b[0]; v[5]=b[1]; v[6]=b[2]; v[7]=b[3];
      } else if (g < 3) {
        f32x4 a = *(const f32x4*)(xr + 64 + g * 8);
        f32x4 b = *(const f32x4*)(xr + 64 + g * 8 + 4);
        v[0]=a[0]; v[1]=a[1]; v[2]=a[2]; v[3]=a[3]; v[4]=b[0]; v[5]=b[1]; v[6]=b[2]; v[7]=b[3];
      } else {
        f32x4 a = *(const f32x4*)(xr + 88);   // 88..91 valid, 92..95 pad
        v[0]=a[0]; v[1]=a[1]; v[2]=a[2]; v[3]=a[3]; v[4]=0.f; v[5]=0.f; v[6]=0.f; v[7]=0.f;
      }
      mk_frag(v, xh[gr][kt], xl[gr][kt]);
    }
  }

  f32x4 ca[2][4];
#pragma unroll
  for (int gr = 0; gr < 2; ++gr)
#pragma unroll
    for (int ct = 0; ct < 4; ++ct)
#pragma unroll
      for (int r = 0; r < 4; ++r) ca[gr][ct][r] = 0.f;
#pragma unroll
  for (int ct = 0; ct < 4; ++ct)
#pragma unroll
    for (int kt = 0; kt < 3; ++kt) {
      s16x8 bh, bl; ldB(WH, WL, 0, kt, ct, 4, l, bh, bl);
      ca[0][ct] = mf3(xh[0][kt], xl[0][kt], bh, bl, ca[0][ct]);
      ca[1][ct] = mf3(xh[1][kt], xl[1][kt], bh, bl, ca[1][ct]);
    }
#pragma unroll
  for (int ct = 0; ct < 4; ++ct) {
    float bv = aeb[16 * ct + m];
#pragma unroll
    for (int r = 0; r < 4; ++r) { ca[0][ct][r] += bv; ca[1][ct][r] += bv; }
  }

  s16x8 ah[2][2], al[2][2];
#pragma unroll
  for (int gr = 0; gr < 2; ++gr) {
    lds_fence();
    c_to_slab<4>(sl, m, g, ca[gr]);
    lds_fence();
    slab_store64(sl, m, g, A0 + (size_t)nat[gr] * 64, ok[gr]);
    slab_frag(sl, m, g, 0, ah[gr][0], al[gr][0]);
    slab_frag(sl, m, g, 1, ah[gr][1], al[gr][1]);
  }

  // s = a0@MW1[0:64] + b1
  f32x4 cs[2][4];
#pragma unroll
  for (int gr = 0; gr < 2; ++gr)
#pragma unroll
    for (int ct = 0; ct < 4; ++ct)
#pragma unroll
      for (int r = 0; r < 4; ++r) cs[gr][ct][r] = 0.f;
#pragma unroll
  for (int ct = 0; ct < 4; ++ct)
#pragma unroll
    for (int kt = 0; kt < 2; ++kt) {
      s16x8 bh, bl; ldB(WH, WL, 6144, kt, ct, 4, l, bh, bl);
      cs[0][ct] = mf3(ah[0][kt], al[0][kt], bh, bl, cs[0][ct]);
      cs[1][ct] = mf3(ah[1][kt], al[1][kt], bh, bl, cs[1][ct]);
    }
#pragma unroll
  for (int ct = 0; ct < 4; ++ct) {
    float bv = b1[16 * ct + m];
#pragma unroll
    for (int r = 0; r < 4; ++r) { cs[0][ct][r] += bv; cs[1][ct][r] += bv; }
  }
#pragma unroll
  for (int gr = 0; gr < 2; ++gr) {
    lds_fence();
    c_to_slab<4>(sl, m, g, cs[gr]);
    lds_fence();
    slab_store64(sl, m, g, S + (size_t)nat[gr] * 64, ok[gr]);
  }

  // t = a0@MW1[64:128]
  f32x4 cT[2][4];
#pragma unroll
  for (int gr = 0; gr < 2; ++gr)
#pragma unroll
    for (int ct = 0; ct < 4; ++ct)
#pragma unroll
      for (int r = 0; r < 4; ++r) cT[gr][ct][r] = 0.f;
#pragma unroll
  for (int ct = 0; ct < 4; ++ct)
#pragma unroll
    for (int kt = 0; kt < 2; ++kt) {
      s16x8 bh, bl; ldB(WH, WL, 6144, kt + 2, ct, 4, l, bh, bl);
      cT[0][ct] = mf3(ah[0][kt], al[0][kt], bh, bl, cT[0][ct]);
      cT[1][ct] = mf3(ah[1][kt], al[1][kt], bh, bl, cT[1][ct]);
    }
#pragma unroll
  for (int gr = 0; gr < 2; ++gr) {
    lds_fence();
    c_to_slab<4>(sl, m, g, cT[gr]);
    lds_fence();
    slab_storeT(sl, m, g, T + (size_t)nat[gr] * 64, ok[gr]);
  }
}

// ---- fused: gather + dense chain (+ next-layer s,t | + fx tail) -----------
template <int HAS_NEXT, int HAS_FX>
__global__ __launch_bounds__(256) void k_dense(
    const float* __restrict__ A, const float* __restrict__ S,
    const unsigned short* __restrict__ T, const int* __restrict__ IDX,
    const unsigned short* __restrict__ WH, const unsigned short* __restrict__ WL,
    int segW2, int segU1, int segU2, int segWn,
    const float* __restrict__ b2, const float* __restrict__ ub1,
    const float* __restrict__ ub2, const float* __restrict__ bn,
    const float* __restrict__ fb1, const float* __restrict__ fb2,
    const float* __restrict__ PW, const float* __restrict__ PB,
    float* __restrict__ Anew, float* __restrict__ Sout,
    unsigned short* __restrict__ Tout,
    float* __restrict__ AF, float* __restrict__ PR) {
  __shared__ float slab[4][HAS_FX ? 128 : 64][17];
  int w = threadIdx.x >> 6, l = threadIdx.x & 63, m = l & 15, g = l >> 4;
  float (*sl)[17] = slab[w];
  int nbase = blockIdx.x * 128 + w * 32;
  int nat[2]; bool ok[2];
#pragma unroll
  for (int gr = 0; gr < 2; ++gr) {
    nat[gr] = nbase + gr * 16 + m;
    ok[gr] = nat[gr] < NA;
    if (!ok[gr]) nat[gr] = NA - 1;
  }

  // gather: H = sum_c relu(s + t[idx]); fragments built directly.
  // lanes sharing m (g=0..3) cover 64B contiguous of each T row -> coalesced.
  s16x8 hh[2][2], hl[2][2];
#pragma unroll
  for (int gr = 0; gr < 2; ++gr) {
    const int* ip = IDX + (size_t)nat[gr] * 12;
    int4 i0 = *(const int4*)ip;
    int4 i1 = *(const int4*)(ip + 4);
    int4 i2 = *(const int4*)(ip + 8);
    int idxs[12] = {i0.x, i0.y, i0.z, i0.w, i1.x, i1.y, i1.z, i1.w,
                    i2.x, i2.y, i2.z, i2.w};
#pragma unroll
    for (int kt = 0; kt < 2; ++kt) {
      int f0 = 32 * kt + 8 * g;
      const float* sp = S + (size_t)nat[gr] * 64 + f0;
      f32x4 s0 = *(const f32x4*)sp;
      f32x4 s1 = *(const f32x4*)(sp + 4);
      float h[8] = {0, 0, 0, 0, 0, 0, 0, 0};
#pragma unroll
      for (int c = 0; c < 12; ++c) {
        uint4 tv = *(const uint4*)(T + (size_t)idxs[c] * 64 + f0);
        h[0] += fmaxf(s0[0] + bf2f((unsigned short)(tv.x & 0xffff)), 0.f);
        h[1] += fmaxf(s0[1] + bf2f((unsigned short)(tv.x >> 16)), 0.f);
        h[2] += fmaxf(s0[2] + bf2f((unsigned short)(tv.y & 0xffff)), 0.f);
        h[3] += fmaxf(s0[3] + bf2f((unsigned short)(tv.y >> 16)), 0.f);
        h[4] += fmaxf(s1[0] + bf2f((unsigned short)(tv.z & 0xffff)), 0.f);
        h[5] += fmaxf(s1[1] + bf2f((unsigned short)(tv.z >> 16)), 0.f);
        h[6] += fmaxf(s1[2] + bf2f((unsigned short)(tv.w & 0xffff)), 0.f);
        h[7] += fmaxf(s1[3] + bf2f((unsigned short)(tv.w >> 16)), 0.f);
      }
      mk_frag(h, hh[gr][kt], hl[gr][kt]);
    }
  }

  // agg = H@W2 + 12*b2
  f32x4 cg[2][4];
#pragma unroll
  for (int gr = 0; gr < 2; ++gr)
#pragma unroll
    for (int ct = 0; ct < 4; ++ct)
#pragma unroll
      for (int r = 0; r < 4; ++r) cg[gr][ct][r] = 0.f;
#pragma unroll
  for (int ct = 0; ct < 4; ++ct)
#pragma unroll
    for (int kt = 0; kt < 2; ++kt) {
      s16x8 bh, bl; ldB(WH, WL, segW2, kt, ct, 4, l, bh, bl);
      cg[0][ct] = mf3(hh[0][kt], hl[0][kt], bh, bl, cg[0][ct]);
      cg[1][ct] = mf3(hh[1][kt], hl[1][kt], bh, bl, cg[1][ct]);
    }
#pragma unroll
  for (int ct = 0; ct < 4; ++ct) {
    float bv = 12.f * b2[16 * ct + m];
#pragma unroll
    for (int r = 0; r < 4; ++r) { cg[0][ct][r] += bv; cg[1][ct][r] += bv; }
  }

  s16x8 qh[2][2], ql[2][2];
#pragma unroll
  for (int gr = 0; gr < 2; ++gr) {
    lds_fence();
    c_to_slab<4>(sl, m, g, cg[gr]);
    lds_fence();
    slab_frag(sl, m, g, 0, qh[gr][0], ql[gr][0]);
    slab_frag(sl, m, g, 1, qh[gr][1], ql[gr][1]);
  }

  s16x8 arh[2][2], arl[2][2];
#pragma unroll
  for (int gr = 0; gr < 2; ++gr)
#pragma unroll
    for (int kt = 0; kt < 2; ++kt)
      ldA_g(A + (size_t)nat[gr] * 64 + kt * 32 + g * 8, arh[gr][kt], arl[gr][kt]);

  // u1 = relu(a@U1[0:64] + agg@U1[64:128] + ub1)
  f32x4 cu[2][4];
#pragma unroll
  for (int gr = 0; gr < 2; ++gr)
#pragma unroll
    for (int ct = 0; ct < 4; ++ct)
#pragma unroll
      for (int r = 0; r < 4; ++r) cu[gr][ct][r] = 0.f;
#pragma unroll
  for (int ct = 0; ct < 4; ++ct) {
#pragma unroll
    for (int kt = 0; kt < 2; ++kt) {
      s16x8 bh, bl; ldB(WH, WL, segU1, kt, ct, 4, l, bh, bl);
      cu[0][ct] = mf3(arh[0][kt], arl[0][kt], bh, bl, cu[0][ct]);
      cu[1][ct] = mf3(arh[1][kt], arl[1][kt], bh, bl, cu[1][ct]);
    }
#pragma unroll
    for (int kt = 0; kt < 2; ++kt) {
      s16x8 bh, bl; ldB(WH, WL, segU1, kt + 2, ct, 4, l, bh, bl);
      cu[0][ct] = mf3(qh[0][kt], ql[0][kt], bh, bl, cu[0][ct]);
      cu[1][ct] = mf3(qh[1][kt], ql[1][kt], bh, bl, cu[1][ct]);
    }
  }
#pragma unroll
  for (int ct = 0; ct < 4; ++ct) {
    float bv = ub1[16 * ct + m];
#pragma unroll
    for (int r = 0; r < 4; ++r) {
      cu[0][ct][r] = fmaxf(cu[0][ct][r] + bv, 0.f);
      cu[1][ct][r] = fmaxf(cu[1][ct][r] + bv, 0.f);
    }
  }

  s16x8 uh[2][2], ul[2][2];
#pragma unroll
  for (int gr = 0; gr < 2; ++gr) {
    lds_fence();
    c_to_slab<4>(sl, m, g, cu[gr]);
    lds_fence();
    slab_frag(sl, m, g, 0, uh[gr][0], ul[gr][0]);
    slab_frag(sl, m, g, 1, uh[gr][1], ul[gr][1]);
  }

  // upd = u1@U2 + ub2 ; a' = relu(a + upd)
  f32x4 cd[2][4];
#pragma unroll
  for (int gr = 0; gr < 2; ++gr)
#pragma unroll
    for (int ct = 0; ct < 4; ++ct)
#pragma unroll
      for (int r = 0; r < 4; ++r) cd[gr][ct][r] = 0.f;
#pragma unroll
  for (int ct = 0; ct < 4; ++ct)
#pragma unroll
    for (int kt = 0; kt < 2; ++kt) {
      s16x8 bh, bl; ldB(WH, WL, segU2, kt, ct, 4, l, bh, bl);
      cd[0][ct] = mf3(uh[0][kt], ul[0][kt], bh, bl, cd[0][ct]);
      cd[1][ct] = mf3(uh[1][kt], ul[1][kt], bh, bl, cd[1][ct]);
    }
#pragma unroll
  for (int ct = 0; ct < 4; ++ct) {
    float bv = ub2[16 * ct + m];
#pragma unroll
    for (int gr = 0; gr < 2; ++gr)
#pragma unroll
      for (int r = 0; r < 4; ++r) {
        int nr = nbase + gr * 16 + 4 * g + r;
        if (nr > NA - 1) nr = NA - 1;
        float av = A[(size_t)nr * 64 + 16 * ct + m];
        cd[gr][ct][r] = fmaxf(av + cd[gr][ct][r] + bv, 0.f);
      }
  }

  s16x8 anh[2][2], anl[2][2];
#pragma unroll
  for (int gr = 0; gr < 2; ++gr) {
    lds_fence();
    c_to_slab<4>(sl, m, g, cd[gr]);
    lds_fence();
    slab_store64(sl, m, g, Anew + (size_t)nat[gr] * 64, ok[gr]);
    if constexpr (HAS_NEXT || HAS_FX) {
      slab_frag(sl, m, g, 0, anh[gr][0], anl[gr][0]);
      slab_frag(sl, m, g, 1, anh[gr][1], anl[gr][1]);
    }
  }

  if constexpr (HAS_NEXT) {
    // s_next
    f32x4 cs[2][4];
#pragma unroll
    for (int gr = 0; gr < 2; ++gr)
#pragma unroll
      for (int ct = 0; ct < 4; ++ct)
#pragma unroll
        for (int r = 0; r < 4; ++r) cs[gr][ct][r] = 0.f;
#pragma unroll
    for (int ct = 0; ct < 4; ++ct)
#pragma unroll
      for (int kt = 0; kt < 2; ++kt) {
        s16x8 bh, bl; ldB(WH, WL, segWn, kt, ct, 4, l, bh, bl);
        cs[0][ct] = mf3(anh[0][kt], anl[0][kt], bh, bl, cs[0][ct]);
        cs[1][ct] = mf3(anh[1][kt], anl[1][kt], bh, bl, cs[1][ct]);
      }
#pragma unroll
    for (int ct = 0; ct < 4; ++ct) {
      float bv = bn[16 * ct + m];
#pragma unroll
      for (int r = 0; r < 4; ++r) { cs[0][ct][r] += bv; cs[1][ct][r] += bv; }
    }
#pragma unroll
    for (int gr = 0; gr < 2; ++gr) {
      lds_fence();
      c_to_slab<4>(sl, m, g, cs[gr]);
      lds_fence();
      slab_store64(sl, m, g, Sout + (size_t)nat[gr] * 64, ok[gr]);
    }
    // t_next
    f32x4 cT[2][4];
#pragma unroll
    for (int gr = 0; gr < 2; ++gr)
#pragma unroll
      for (int ct = 0; ct < 4; ++ct)
#pragma unroll
        for (int r = 0; r < 4; ++r) cT[gr][ct][r] = 0.f;
#pragma unroll
    for (int ct = 0; ct < 4; ++ct)
#pragma unroll
      for (int kt = 0; kt < 2; ++kt) {
        s16x8 bh, bl; ldB(WH, WL, segWn, kt + 2, ct, 4, l, bh, bl);
        cT[0][ct] = mf3(anh[0][kt], anl[0][kt], bh, bl, cT[0][ct]);
        cT[1][ct] = mf3(anh[1][kt], anl[1][kt], bh, bl, cT[1][ct]);
      }
#pragma unroll
    for (int gr = 0; gr < 2; ++gr) {
      lds_fence();
      c_to_slab<4>(sl, m, g, cT[gr]);
      lds_fence();
      slab_storeT(sl, m, g, Tout + (size_t)nat[gr] * 64, ok[gr]);
    }
  }

  if constexpr (HAS_FX) {
    // h = relu(raw@FX1 + fb1)  (128 wide)
    f32x4 ch[2][8];
#pragma unroll
    for (int gr = 0; gr < 2; ++gr)
#pragma unroll
      for (int ct = 0; ct < 8; ++ct)
#pragma unroll
        for (int r = 0; r < 4; ++r) ch[gr][ct][r] = 0.f;
#pragma unroll
    for (int ct = 0; ct < 8; ++ct)
#pragma unroll
      for (int kt = 0; kt < 2; ++kt) {
        s16x8 bh, bl; ldB(WH, WL, 79872, kt, ct, 8, l, bh, bl);
        ch[0][ct] = mf3(anh[0][kt], anl[0][kt], bh, bl, ch[0][ct]);
        ch[1][ct] = mf3(anh[1][kt], anl[1][kt], bh, bl, ch[1][ct]);
      }
#pragma unroll
    for (int ct = 0; ct < 8; ++ct) {
      float bv = fb1[16 * ct + m];
#pragma unroll
      for (int r = 0; r < 4; ++r) {
        ch[0][ct][r] = fmaxf(ch[0][ct][r] + bv, 0.f);
        ch[1][ct][r] = fmaxf(ch[1][ct][r] + bv, 0.f);
      }
    }

    s16x8 hfh[2][4], hfl[2][4];
#pragma unroll
    for (int gr = 0; gr < 2; ++gr) {
      lds_fence();
      c_to_slab<8>(sl, m, g, ch[gr]);
      lds_fence();
#pragma unroll
      for (int kt = 0; kt < 4; ++kt) slab_frag(sl, m, g, kt, hfh[gr][kt], hfl[gr][kt]);
    }

    // af = h@FX2 + fb2
    f32x4 cf[2][4];
#pragma unroll
    for (int gr = 0; gr < 2; ++gr)
#pragma unroll
      for (int ct = 0; ct < 4; ++ct)
#pragma unroll
        for (int r = 0; r < 4; ++r) cf[gr][ct][r] = 0.f;
#pragma unroll
    for (int ct = 0; ct < 4; ++ct)
#pragma unroll
      for (int kt = 0; kt < 4; ++kt) {
        s16x8 bh, bl; ldB(WH, WL, 88064, kt, ct, 4, l, bh, bl);
        cf[0][ct] = mf3(hfh[0][kt], hfl[0][kt], bh, bl, cf[0][ct]);
        cf[1][ct] = mf3(hfh[1][kt], hfl[1][kt], bh, bl, cf[1][ct]);
      }
#pragma unroll
    for (int ct = 0; ct < 4; ++ct) {
      float bv = fb2[16 * ct + m];
#pragma unroll
      for (int r = 0; r < 4; ++r) { cf[0][ct][r] += bv; cf[1][ct][r] += bv; }
    }

#pragma unroll
    for (int gr = 0; gr < 2; ++gr) {
      lds_fence();
      c_to_slab<4>(sl, m, g, cf[gr]);
      lds_fence();
      slab_store64(sl, m, g, AF + (size_t)nat[gr] * 64, ok[gr]);
      float acc = PB[g];
#pragma unroll 8
      for (int f = 0; f < 64; ++f) acc += sl[f][m] * PW[g * 64 + f];
      if (ok[gr]) PR[(size_t)nat[gr] * 4 + g] = acc;
    }
  }
}

extern "C" void kernel_launch(void* const* d_in, const int* in_sizes, int n_in,
                              void* d_out, int out_size, void* d_ws, size_t ws_size,
                              hipStream_t stream) {
  const float* atom_fea = (const float*)d_in[0];
  const int*   nbr_idx  = (const int*)d_in[2];
  const float* ae_w   = (const float*)d_in[3];
  const float* ae_b   = (const float*)d_in[4];
  const float* msg_w1 = (const float*)d_in[7];
  const float* msg_b1 = (const float*)d_in[8];
  const float* msg_w2 = (const float*)d_in[9];
  const float* msg_b2 = (const float*)d_in[10];
  const float* upd_w1 = (const float*)d_in[11];
  const float* upd_b1 = (const float*)d_in[12];
  const float* upd_w2 = (const float*)d_in[13];
  const float* upd_b2 = (const float*)d_in[14];
  const float* fx_w1  = (const float*)d_in[15];
  const float* fx_b1  = (const float*)d_in[16];
  const float* fx_w2  = (const float*)d_in[17];
  const float* fx_b2  = (const float*)d_in[18];
  const float* prop_w = (const float*)d_in[19];
  const float* prop_b = (const float*)d_in[20];

  float* props   = (float*)d_out;
  float* af_reg  = props + (size_t)NA * 4;
  float* raw_reg = af_reg + (size_t)NA * 64;
  float* S0 = (float*)d_ws;
  float* S1 = S0 + (size_t)NA * 64;
  unsigned short* T0 = (unsigned short*)(S1 + (size_t)NA * 64);
  unsigned short* T1 = T0 + (size_t)NA * 64;
  unsigned short* WHp = T1 + (size_t)NA * 64;
  unsigned short* WLp = WHp + 96256;

  k_prep<<<376, 256, 0, stream>>>(ae_w, msg_w1, msg_w2, upd_w1, upd_w2,
                                  fx_w1, fx_w2, WHp, WLp);

  int ngrid = (NA + 127) / 128;   // 2344
  k_embed_st<<<ngrid, 256, 0, stream>>>(atom_fea, WHp, WLp, ae_b, msg_b1,
                                        af_reg, S0, T0);

  const int base0 = 6144, base1 = 6144 + 24576, base2 = 6144 + 2 * 24576;

  // layer 0: A0(af_reg) -> A1(raw_reg); S0/T0 -> S1/T1
  k_dense<1, 0><<<ngrid, 256, 0, stream>>>(
      af_reg, S0, T0, nbr_idx, WHp, WLp,
      base0 + 8192, base0 + 12288, base0 + 20480, base1,
      msg_b2, upd_b1, upd_b2, msg_b1 + 64,
      fx_b1, fx_b2, prop_w, prop_b,
      raw_reg, S1, T1, nullptr, nullptr);

  // layer 1: A1(raw_reg) -> A2(af_reg); S1/T1 -> S0/T0
  k_dense<1, 0><<<ngrid, 256, 0, stream>>>(
      raw_reg, S1, T1, nbr_idx, WHp, WLp,
      base1 + 8192, base1 + 12288, base1 + 20480, base2,
      msg_b2 + 64, upd_b1 + 64, upd_b2 + 64, msg_b1 + 128,
      fx_b1, fx_b2, prop_w, prop_b,
      af_reg, S0, T0, nullptr, nullptr);

  // layer 2 + fx: A2(af_reg) -> raw(raw_reg); af->af_reg, props->d_out
  k_dense<0, 1><<<ngrid, 256, 0, stream>>>(
      af_reg, S0, T0, nbr_idx, WHp, WLp,
      base2 + 8192, base2 + 12288, base2 + 20480, 0,
      msg_b2 + 128, upd_b1 + 128, upd_b2 + 128, msg_b1,
      fx_b1, fx_b2, prop_w, prop_b,
      raw_reg, S1, T1, af_reg, props);
}